// Round 6
// baseline (480.347 us; speedup 1.0000x reference)
//
#include <hip/hip_runtime.h>
#include <hip/hip_bf16.h>

typedef unsigned short u16;
typedef unsigned int   u32;

#define B_  16
#define N_  5000
#define F_  512
#define C_  64
#define FC_ 128
#define NT  (B_ * N_)   // 80000 total nodes
#define RB  64          // rows per block in gemm1 (NT % RB == 0 -> 1250 blocks)

__device__ __forceinline__ float bf2f(u16 h) {
    return __uint_as_float(((u32)h) << 16);
}
__device__ __forceinline__ u16 f2bf(float f) {
    union { __hip_bfloat16 h; u16 s; } c; c.h = __float2bfloat16(f); return c.s;
}
__device__ __forceinline__ float ldw(const void* p, int i, int fF) {
    return fF ? bf2f(((const u16*)p)[i]) : ((const float*)p)[i];
}

// ---------------------------------------------------------------------------
// setup_k (1 block, 256 thr): dtype detection + deg zeroing + weight convert.
// flags[0]=1 -> float tensors are bf16 (else fp32); flags[1]=1 -> int64 index.
// ---------------------------------------------------------------------------
__global__ __launch_bounds__(256) void setup_k(
    const u32* __restrict__ x32, const u32* __restrict__ ei32,
    const void* __restrict__ W1, const void* __restrict__ W2,
    const void* __restrict__ fcw, const void* __restrict__ cw1,
    const void* __restrict__ cw2, const void* __restrict__ b1,
    const void* __restrict__ b2, const void* __restrict__ fcb,
    const void* __restrict__ cb1, const void* __restrict__ cb2,
    int* __restrict__ flags, int* __restrict__ deg,
    float* __restrict__ w1f, float* __restrict__ w2f, float* __restrict__ fcwf,
    float* __restrict__ cw1f, float* __restrict__ cw2f, float* __restrict__ b1f,
    float* __restrict__ b2f, float* __restrict__ fcbf, float* __restrict__ cb1f,
    float* __restrict__ cb2f)
{
    __shared__ int s_cnt, s_fF;
    int t = threadIdx.x;
    if (t == 0) s_cnt = 0;
    __syncthreads();
    u32 w = x32[t];
    int e = (int)((w >> 7) & 0xffu);
    if (e >= 112 && e <= 136) atomicAdd(&s_cnt, 1);
    __syncthreads();
    if (t == 0) {
        int fF = (s_cnt >= 128) ? 1 : 0;
        s_fF = fF;
        flags[0] = fF;
        u32 orv = 0;
        for (int i = 1; i < 64; i += 2) orv |= ei32[i];   // 32 odd words
        flags[1] = (orv == 0u) ? 1 : 0;
    }
    for (int i = t; i < N_; i += 256) deg[i] = 0;
    __syncthreads();
    int fF = s_fF;
    for (int i = t; i < 10578; i += 256) {
        int u = i;
        if (u < 8192) { w1f[u] = ldw(W1, u, fF); continue; }  u -= 8192;
        if (u < 256)  { w2f[u]  = ldw(W2, u, fF);  continue; }  u -= 256;
        if (u < 16)   { fcwf[u] = ldw(fcw, u, fF); continue; }  u -= 16;
        if (u < 2048) { cw1f[u] = ldw(cw1, u, fF); continue; }  u -= 2048;
        if (u < 16)   { cw2f[u] = ldw(cw2, u, fF); continue; }  u -= 16;
        if (u < 16)   { b1f[u]  = ldw(b1, u, fF);  continue; }  u -= 16;
        if (u < 16)   { b2f[u]  = ldw(b2, u, fF);  continue; }  u -= 16;
        if (u < 1)    { fcbf[u] = ldw(fcb, u, fF); continue; }  u -= 1;
        if (u < 16)   { cb1f[u] = ldw(cb1, u, fF); continue; }  u -= 16;
        if (u < 1)    { cb2f[u] = ldw(cb2, u, fF); continue; }
    }
}

// edge index accessors (ei32 = edge_index buffer viewed as u32)
__device__ __forceinline__ int src_at(const u32* ei32, int t, int E, int fI) {
    return (int)(fI ? ei32[2 * t] : ei32[t]);
}
__device__ __forceinline__ int dst_at(const u32* ei32, int t, int E, int fI) {
    return (int)(fI ? ei32[2 * (E + t)] : ei32[E + t]);
}

// ---------------------------------------------------------------------------
// degcol_k: blocks [0, colB0) count degrees; blocks [colB0, colB0+4) run the
// column MLP (it only needs weights converted by setup_k). Saves one launch.
// ---------------------------------------------------------------------------
__global__ __launch_bounds__(256) void degcol_k(
    const u32* __restrict__ ei32, const int* __restrict__ flags,
    int* __restrict__ deg, int E, int colB0,
    const void* __restrict__ cfraw,
    const float* __restrict__ cw1f, const float* __restrict__ cb1f,
    const float* __restrict__ cw2f, const float* __restrict__ cb2f,
    float* __restrict__ cl)
{
    if ((int)blockIdx.x < colB0) {
        int t = blockIdx.x * 256 + threadIdx.x;
        if (t >= E) return;
        int d = dst_at(ei32, t, E, flags[1]);
        if ((unsigned)d < (unsigned)N_) atomicAdd(&deg[d], 1);
        return;
    }
    // ---- column MLP: cl[b,c] = (relu(cf[b,c,:] @ cw1 + cb1)) @ cw2 + cb2
    int t = (blockIdx.x - colB0) * 256 + threadIdx.x;
    if (t >= B_ * C_) return;
    float acc[16];
#pragma unroll
    for (int k = 0; k < 16; k++) acc[k] = cb1f[k];
    if (flags[0]) {
        const u16* r = (const u16*)cfraw + (size_t)t * FC_;
        for (int f = 0; f < FC_; f += 8) {
            uint4 pk = *(const uint4*)(r + f);
            u32 q[4] = {pk.x, pk.y, pk.z, pk.w};
#pragma unroll
            for (int j = 0; j < 4; j++) {
                float v0 = bf2f((u16)(q[j] & 0xffffu));
                float v1 = bf2f((u16)(q[j] >> 16));
                const float* w0 = cw1f + (f + 2 * j) * 16;
#pragma unroll
                for (int k = 0; k < 16; k++) acc[k] += v0 * w0[k];
#pragma unroll
                for (int k = 0; k < 16; k++) acc[k] += v1 * w0[16 + k];
            }
        }
    } else {
        const float* r = (const float*)cfraw + (size_t)t * FC_;
        for (int f = 0; f < FC_; f += 4) {
            float4 a = *(const float4*)(r + f);
            float v[4] = {a.x, a.y, a.z, a.w};
#pragma unroll
            for (int j = 0; j < 4; j++) {
                const float* w0 = cw1f + (f + j) * 16;
#pragma unroll
                for (int k = 0; k < 16; k++) acc[k] += v[j] * w0[k];
            }
        }
    }
    float s = cb2f[0];
#pragma unroll
    for (int k = 0; k < 16; k++) s += fmaxf(acc[k], 0.0f) * cw2f[k];
    cl[t] = s;
}

// ---------------------------------------------------------------------------
// Single-block exclusive scan over deg[5000] -> rowptr/cursor, plus dinv.
// ---------------------------------------------------------------------------
__global__ __launch_bounds__(1024) void scan_k(const int* __restrict__ deg,
                                               int* __restrict__ rowptr,
                                               int* __restrict__ cursor,
                                               float* __restrict__ dinv)
{
    __shared__ int ssum[1024];
    int t = threadIdx.x;
    int base = t * 5;
    int loc[5];
    int run = 0;
#pragma unroll
    for (int i = 0; i < 5; i++) {
        int idx = base + i;
        int v = (idx < N_) ? deg[idx] : 0;
        loc[i] = run;
        run += v;
    }
    ssum[t] = run;
    __syncthreads();
    for (int offs = 1; offs < 1024; offs <<= 1) {
        int v = (t >= offs) ? ssum[t - offs] : 0;
        __syncthreads();
        ssum[t] += v;
        __syncthreads();
    }
    int exclusive = ssum[t] - run;
#pragma unroll
    for (int i = 0; i < 5; i++) {
        int idx = base + i;
        if (idx < N_) {
            int rp = exclusive + loc[i];
            rowptr[idx] = rp;
            cursor[idx] = rp;
            dinv[idx] = 1.0f / sqrtf((float)deg[idx] + 1.0f);  // +1 self loop
        }
    }
    if (t == 1023) rowptr[N_] = ssum[1023];
}

// ---------------------------------------------------------------------------
__global__ __launch_bounds__(256) void fill_k(const u32* __restrict__ ei32,
                                              const int* __restrict__ flags,
                                              int* __restrict__ cursor,
                                              int* __restrict__ csr, int E)
{
    int t = blockIdx.x * blockDim.x + threadIdx.x;
    if (t >= E) return;
    int fI = flags[1];
    int s = src_at(ei32, t, E, fI);
    int d = dst_at(ei32, t, E, fI);
    if ((unsigned)d >= (unsigned)N_) return;
    if ((unsigned)s >= (unsigned)N_) s = 0;
    int pos = atomicAdd(&cursor[d], 1);
    if ((unsigned)pos < (unsigned)E) csr[pos] = s;
}

// ---------------------------------------------------------------------------
// GEMM1 v3: H'[b,n,k] = dinv[n] * sum_f x[b,n,f] * W1[f,k]
// 256 threads = 4 waves per 64-row tile; K split BY WAVE (wave w owns
// k = w*8+m within each 32-chunk) so W1 rows stay wave-uniform (s_load) and
// each wave's 64 lanes each own one row. Cross-wave reduce via LDS at end.
//  - staging coalesced; LDS stride 33 -> compute reads 2-way conflicts (free)
//  - 4 blocks/CU (33.8 KB LDS) = 16 waves/CU; ~32 KB staging loads in flight
// ---------------------------------------------------------------------------
__global__ __launch_bounds__(256) void gemm1_k(const void* __restrict__ xraw,
                                               const float* __restrict__ w1f,
                                               const float* __restrict__ dinv,
                                               const int* __restrict__ flags,
                                               u16* __restrict__ out)
{
    __shared__ float xs[RB * 33];        // 8448 floats = 33.8 KB
    int t = threadIdx.x;
    int w = t >> 6;                      // wave 0..3
    int l = t & 63;                      // lane = row within tile (compute)
    int row0 = blockIdx.x * RB;
    int fF = flags[0];
    float acc[16];
#pragma unroll
    for (int c = 0; c < 16; c++) acc[c] = 0.0f;

    for (int f0 = 0; f0 < F_; f0 += 32) {
        if (fF) {   // bf16: 64 rows x 32 elems = 256 uint4, 1 per thread
            int r = t >> 2, c8 = (t & 3) * 8;
            const u16* p = (const u16*)xraw + (size_t)(row0 + r) * F_ + f0 + c8;
            uint4 pk = *(const uint4*)p;
            u32 q[4] = {pk.x, pk.y, pk.z, pk.w};
            float* dst = xs + r * 33 + c8;
#pragma unroll
            for (int m = 0; m < 4; m++) {
                dst[2 * m]     = bf2f((u16)(q[m] & 0xffffu));
                dst[2 * m + 1] = bf2f((u16)(q[m] >> 16));
            }
        } else {    // fp32: 64 rows x 32 elems = 512 float4, 2 per thread
#pragma unroll
            for (int j = 0; j < 2; j++) {
                int idx = t + 256 * j;
                int r = idx >> 3, c4 = (idx & 7) * 4;
                const float* p = (const float*)xraw + (size_t)(row0 + r) * F_ + f0 + c4;
                float4 v = *(const float4*)p;
                float* dst = xs + r * 33 + c4;
                dst[0] = v.x; dst[1] = v.y; dst[2] = v.z; dst[3] = v.w;
            }
        }
        __syncthreads();
        const float* xr = xs + l * 33 + w * 8;
#pragma unroll
        for (int m = 0; m < 8; m++) {
            float xv = xr[m];
            const float* wr = w1f + (f0 + w * 8 + m) * 16;   // wave-uniform
#pragma unroll
            for (int c = 0; c < 16; c++) acc[c] += xv * wr[c];
        }
        __syncthreads();
    }

    // cross-wave reduction: waves 1..3 park partials in LDS, wave 0 sums.
    if (w > 0) {
        float* dst = xs + ((w - 1) * 64 + l) * 16;
#pragma unroll
        for (int c = 0; c < 16; c += 4) {
            *(float4*)(dst + c) = make_float4(acc[c], acc[c + 1], acc[c + 2], acc[c + 3]);
        }
    }
    __syncthreads();
    if (w == 0) {
#pragma unroll
        for (int c = 0; c < 16; c++) {
            acc[c] += xs[(0 * 64 + l) * 16 + c]
                    + xs[(1 * 64 + l) * 16 + c]
                    + xs[(2 * 64 + l) * 16 + c];
        }
        int row = row0 + l;
        float s = dinv[row % N_];
        union { uint4 u; u16 h[8]; } o0, o1;
#pragma unroll
        for (int c = 0; c < 8; c++) o0.h[c] = f2bf(acc[c] * s);
#pragma unroll
        for (int c = 0; c < 8; c++) o1.h[c] = f2bf(acc[8 + c] * s);
        uint4* op = (uint4*)(out + (size_t)row * 16);
        op[0] = o0.u;
        op[1] = o1.u;
    }
}

// ---------------------------------------------------------------------------
// Fused agg1 + gemm2: one WAVE per (b,d); lanes = 16 features x 4 edge slots.
//   x1[k] = relu(dinv[d]*(H'[b,d,k] + sum_{s->d} H'[b,s,k]) + b1[k])
//   H2'[b,d,kk] = dinv[d] * sum_k x1[k]*W2[k,kk]
// ---------------------------------------------------------------------------
__global__ __launch_bounds__(256) void agg12_k(const u16* __restrict__ h,
                                               const int* __restrict__ rowptr,
                                               const int* __restrict__ csr,
                                               const float* __restrict__ dinv,
                                               const float* __restrict__ b1f,
                                               const float* __restrict__ w2f,
                                               u16* __restrict__ out)
{
    int wid = blockIdx.x * 4 + (threadIdx.x >> 6);   // wave id = b*N + d
    int lane = threadIdx.x & 63;
    int k = lane & 15, j = lane >> 4;
    int d = wid % N_;
    int b = wid / N_;
    const u16* hb = h + (size_t)b * N_ * 16;
    float acc = (j == 0) ? bf2f(hb[d * 16 + k]) : 0.0f;   // self loop
    int e0 = rowptr[d], e1 = rowptr[d + 1];
    for (int e = e0 + j; e < e1; e += 4) {
        int s = csr[e];
        acc += bf2f(hb[s * 16 + k]);
    }
    acc += __shfl_xor(acc, 16);            // reduce over 4 edge slots
    acc += __shfl_xor(acc, 32);
    float dv = dinv[d];
    float x1 = fmaxf(acc * dv + b1f[k], 0.0f);
    float a2 = 0.0f;
#pragma unroll
    for (int kk = 0; kk < 16; kk++) {
        float xv = __shfl(x1, kk, 16);     // broadcast x1[kk] within 16-group
        a2 += xv * w2f[kk * 16 + k];
    }
    if (lane < 16) out[(size_t)wid * 16 + k] = f2bf(a2 * dv);
}

// ---------------------------------------------------------------------------
// Fused agg2 + node head + join: one WAVE per (b,d).
//   x2[k] = relu(dinv[d]*(H2'[b,d,k] + sum_s H2'[b,s,k]) + b2[k])
//   nl = sum_k x2[k]*fc_w[k] + fc_b
//   out[b, d*64 + c] = nl + cl[b,c]   (lane c writes, coalesced row)
// ---------------------------------------------------------------------------
__global__ __launch_bounds__(256) void agg2join_k(const u16* __restrict__ h,
                                                  const int* __restrict__ rowptr,
                                                  const int* __restrict__ csr,
                                                  const float* __restrict__ dinv,
                                                  const float* __restrict__ b2f,
                                                  const float* __restrict__ fcwf,
                                                  const float* __restrict__ fcbf,
                                                  const float* __restrict__ cl,
                                                  const int* __restrict__ flags,
                                                  void* __restrict__ outraw)
{
    int wid = blockIdx.x * 4 + (threadIdx.x >> 6);   // wave id = b*N + d
    int lane = threadIdx.x & 63;
    int k = lane & 15, j = lane >> 4;
    int d = wid % N_;
    int b = wid / N_;
    const u16* hb = h + (size_t)b * N_ * 16;
    float acc = (j == 0) ? bf2f(hb[d * 16 + k]) : 0.0f;
    int e0 = rowptr[d], e1 = rowptr[d + 1];
    for (int e = e0 + j; e < e1; e += 4) {
        int s = csr[e];
        acc += bf2f(hb[s * 16 + k]);
    }
    acc += __shfl_xor(acc, 16);
    acc += __shfl_xor(acc, 32);
    float x2 = fmaxf(acc * dinv[d] + b2f[k], 0.0f);
    float p = x2 * fcwf[k];
    p += __shfl_xor(p, 8, 16);
    p += __shfl_xor(p, 4, 16);
    p += __shfl_xor(p, 2, 16);
    p += __shfl_xor(p, 1, 16);             // all lanes now hold nl
    float nlv = p + fcbf[0];
    float res = nlv + cl[b * C_ + lane];   // lane = column c
    size_t idx = (size_t)wid * C_ + lane;
    if (flags[0]) ((u16*)outraw)[idx] = f2bf(res);
    else          ((float*)outraw)[idx] = res;
}

// ---------------------------------------------------------------------------
extern "C" void kernel_launch(void* const* d_in, const int* in_sizes, int n_in,
                              void* d_out, int out_size, void* d_ws, size_t ws_size,
                              hipStream_t stream)
{
    const void* x    = d_in[0];
    const void* cf   = d_in[1];
    const u32*  ei32 = (const u32*)d_in[2];
    const void* W1   = d_in[3];
    const void* b1   = d_in[4];
    const void* W2   = d_in[5];
    const void* b2   = d_in[6];
    const void* fcw  = d_in[7];
    const void* fcb  = d_in[8];
    const void* cw1  = d_in[9];
    const void* cb1  = d_in[10];
    const void* cw2  = d_in[11];
    const void* cb2  = d_in[12];

    const int E = in_sizes[2] / 2;

    char* base = (char*)d_ws;
    size_t off = 0;
    auto alloc = [&](size_t bytes) -> void* {
        void* p = base + off;
        off = (off + bytes + 255) & ~(size_t)255;
        return p;
    };
    int*   flags  = (int*)alloc(2 * 4);
    float* w1f  = (float*)alloc(8192 * 4);
    float* w2f  = (float*)alloc(256 * 4);
    float* fcwf = (float*)alloc(16 * 4);
    float* cw1f = (float*)alloc(2048 * 4);
    float* cw2f = (float*)alloc(16 * 4);
    float* b1f  = (float*)alloc(16 * 4);
    float* b2f  = (float*)alloc(16 * 4);
    float* fcbf = (float*)alloc(4);
    float* cb1f = (float*)alloc(16 * 4);
    float* cb2f = (float*)alloc(4);
    int*   deg    = (int*)alloc((size_t)N_ * 4);
    int*   rowptr = (int*)alloc((size_t)(N_ + 1) * 4);
    int*   cursor = (int*)alloc((size_t)N_ * 4);
    float* dinv   = (float*)alloc((size_t)N_ * 4);
    int*   csr    = (int*)alloc((size_t)E * 4);
    u16*   bufA = (u16*)alloc((size_t)NT * 16 * 2);   // H'  (bf16)
    u16*   bufB = (u16*)alloc((size_t)NT * 16 * 2);   // H2' (bf16)
    float* cl   = (float*)alloc((size_t)B_ * C_ * 4);

    const int colB0 = (E + 255) / 256;   // deg blocks; col blocks appended

    setup_k<<<1, 256, 0, stream>>>(
        (const u32*)x, ei32, W1, W2, fcw, cw1, cw2, b1, b2, fcb, cb1, cb2,
        flags, deg,
        w1f, w2f, fcwf, cw1f, cw2f, b1f, b2f, fcbf, cb1f, cb2f);
    degcol_k<<<colB0 + (B_ * C_ + 255) / 256, 256, 0, stream>>>(
        ei32, flags, deg, E, colB0, cf, cw1f, cb1f, cw2f, cb2f, cl);
    scan_k<<<1, 1024, 0, stream>>>(deg, rowptr, cursor, dinv);
    fill_k<<<(E + 255) / 256, 256, 0, stream>>>(ei32, flags, cursor, csr, E);

    gemm1_k<<<NT / RB, 256, 0, stream>>>(x, w1f, dinv, flags, bufA);
    agg12_k<<<NT / 4, 256, 0, stream>>>(bufA, rowptr, csr, dinv, b1f, w2f, bufB);
    agg2join_k<<<NT / 4, 256, 0, stream>>>(bufB, rowptr, csr, dinv, b2f, fcwf, fcbf, cl, flags, d_out);
}

// Round 7
// 439.666 us; speedup vs baseline: 1.0925x; 1.0925x over previous
//
#include <hip/hip_runtime.h>
#include <hip/hip_bf16.h>

typedef unsigned short u16;
typedef unsigned int   u32;

#define B_  16
#define N_  5000
#define F_  512
#define C_  64
#define FC_ 128
#define NT  (B_ * N_)   // 80000 total nodes
#define RB  64          // rows per block in gemm1 -> 1250 blocks
#define RSTR 20         // LDS reduce stride (words): 80 B, b128-aligned

__device__ __forceinline__ float bf2f(u16 h) {
    return __uint_as_float(((u32)h) << 16);
}
__device__ __forceinline__ u16 f2bf(float f) {
    union { __hip_bfloat16 h; u16 s; } c; c.h = __float2bfloat16(f); return c.s;
}
__device__ __forceinline__ float ldw(const void* p, int i, int fF) {
    return fF ? bf2f(((const u16*)p)[i]) : ((const float*)p)[i];
}

// ---------------------------------------------------------------------------
// setup_k (1 block, 256 thr): dtype detection + deg zeroing + weight convert.
// flags[0]=1 -> float tensors are bf16 (else fp32); flags[1]=1 -> int64 index.
// ---------------------------------------------------------------------------
__global__ __launch_bounds__(256) void setup_k(
    const u32* __restrict__ x32, const u32* __restrict__ ei32,
    const void* __restrict__ W1, const void* __restrict__ W2,
    const void* __restrict__ fcw, const void* __restrict__ cw1,
    const void* __restrict__ cw2, const void* __restrict__ b1,
    const void* __restrict__ b2, const void* __restrict__ fcb,
    const void* __restrict__ cb1, const void* __restrict__ cb2,
    int* __restrict__ flags, int* __restrict__ deg,
    float* __restrict__ w1f, float* __restrict__ w2f, float* __restrict__ fcwf,
    float* __restrict__ cw1f, float* __restrict__ cw2f, float* __restrict__ b1f,
    float* __restrict__ b2f, float* __restrict__ fcbf, float* __restrict__ cb1f,
    float* __restrict__ cb2f)
{
    __shared__ int s_cnt, s_fF;
    int t = threadIdx.x;
    if (t == 0) s_cnt = 0;
    __syncthreads();
    u32 w = x32[t];
    int e = (int)((w >> 7) & 0xffu);
    if (e >= 112 && e <= 136) atomicAdd(&s_cnt, 1);
    __syncthreads();
    if (t == 0) {
        int fF = (s_cnt >= 128) ? 1 : 0;
        s_fF = fF;
        flags[0] = fF;
        u32 orv = 0;
        for (int i = 1; i < 64; i += 2) orv |= ei32[i];   // 32 odd words
        flags[1] = (orv == 0u) ? 1 : 0;
    }
    for (int i = t; i < N_; i += 256) deg[i] = 0;
    __syncthreads();
    int fF = s_fF;
    for (int i = t; i < 10578; i += 256) {
        int u = i;
        if (u < 8192) { w1f[u] = ldw(W1, u, fF); continue; }  u -= 8192;
        if (u < 256)  { w2f[u]  = ldw(W2, u, fF);  continue; }  u -= 256;
        if (u < 16)   { fcwf[u] = ldw(fcw, u, fF); continue; }  u -= 16;
        if (u < 2048) { cw1f[u] = ldw(cw1, u, fF); continue; }  u -= 2048;
        if (u < 16)   { cw2f[u] = ldw(cw2, u, fF); continue; }  u -= 16;
        if (u < 16)   { b1f[u]  = ldw(b1, u, fF);  continue; }  u -= 16;
        if (u < 16)   { b2f[u]  = ldw(b2, u, fF);  continue; }  u -= 16;
        if (u < 1)    { fcbf[u] = ldw(fcb, u, fF); continue; }  u -= 1;
        if (u < 16)   { cb1f[u] = ldw(cb1, u, fF); continue; }  u -= 16;
        if (u < 1)    { cb2f[u] = ldw(cb2, u, fF); continue; }
    }
}

// edge index accessors (ei32 = edge_index buffer viewed as u32)
__device__ __forceinline__ int src_at(const u32* ei32, int t, int E, int fI) {
    return (int)(fI ? ei32[2 * t] : ei32[t]);
}
__device__ __forceinline__ int dst_at(const u32* ei32, int t, int E, int fI) {
    return (int)(fI ? ei32[2 * (E + t)] : ei32[E + t]);
}

// ---------------------------------------------------------------------------
// degcol_k: blocks [0, colB0) count degrees; blocks [colB0, ...) run the
// column MLP (it only needs weights converted by setup_k).
// ---------------------------------------------------------------------------
__global__ __launch_bounds__(256) void degcol_k(
    const u32* __restrict__ ei32, const int* __restrict__ flags,
    int* __restrict__ deg, int E, int colB0,
    const void* __restrict__ cfraw,
    const float* __restrict__ cw1f, const float* __restrict__ cb1f,
    const float* __restrict__ cw2f, const float* __restrict__ cb2f,
    float* __restrict__ cl)
{
    if ((int)blockIdx.x < colB0) {
        int t = blockIdx.x * 256 + threadIdx.x;
        if (t >= E) return;
        int d = dst_at(ei32, t, E, flags[1]);
        if ((unsigned)d < (unsigned)N_) atomicAdd(&deg[d], 1);
        return;
    }
    // ---- column MLP: cl[b,c] = (relu(cf[b,c,:] @ cw1 + cb1)) @ cw2 + cb2
    int t = (blockIdx.x - colB0) * 256 + threadIdx.x;
    if (t >= B_ * C_) return;
    float acc[16];
#pragma unroll
    for (int k = 0; k < 16; k++) acc[k] = cb1f[k];
    if (flags[0]) {
        const u16* r = (const u16*)cfraw + (size_t)t * FC_;
        for (int f = 0; f < FC_; f += 8) {
            uint4 pk = *(const uint4*)(r + f);
            u32 q[4] = {pk.x, pk.y, pk.z, pk.w};
#pragma unroll
            for (int j = 0; j < 4; j++) {
                float v0 = bf2f((u16)(q[j] & 0xffffu));
                float v1 = bf2f((u16)(q[j] >> 16));
                const float* w0 = cw1f + (f + 2 * j) * 16;
#pragma unroll
                for (int k = 0; k < 16; k++) acc[k] += v0 * w0[k];
#pragma unroll
                for (int k = 0; k < 16; k++) acc[k] += v1 * w0[16 + k];
            }
        }
    } else {
        const float* r = (const float*)cfraw + (size_t)t * FC_;
        for (int f = 0; f < FC_; f += 4) {
            float4 a = *(const float4*)(r + f);
            float v[4] = {a.x, a.y, a.z, a.w};
#pragma unroll
            for (int j = 0; j < 4; j++) {
                const float* w0 = cw1f + (f + j) * 16;
#pragma unroll
                for (int k = 0; k < 16; k++) acc[k] += v[j] * w0[k];
            }
        }
    }
    float s = cb2f[0];
#pragma unroll
    for (int k = 0; k < 16; k++) s += fmaxf(acc[k], 0.0f) * cw2f[k];
    cl[t] = s;
}

// ---------------------------------------------------------------------------
// Single-block exclusive scan over deg[5000] -> rowptr/cursor, plus dinv.
// ---------------------------------------------------------------------------
__global__ __launch_bounds__(1024) void scan_k(const int* __restrict__ deg,
                                               int* __restrict__ rowptr,
                                               int* __restrict__ cursor,
                                               float* __restrict__ dinv)
{
    __shared__ int ssum[1024];
    int t = threadIdx.x;
    int base = t * 5;
    int loc[5];
    int run = 0;
#pragma unroll
    for (int i = 0; i < 5; i++) {
        int idx = base + i;
        int v = (idx < N_) ? deg[idx] : 0;
        loc[i] = run;
        run += v;
    }
    ssum[t] = run;
    __syncthreads();
    for (int offs = 1; offs < 1024; offs <<= 1) {
        int v = (t >= offs) ? ssum[t - offs] : 0;
        __syncthreads();
        ssum[t] += v;
        __syncthreads();
    }
    int exclusive = ssum[t] - run;
#pragma unroll
    for (int i = 0; i < 5; i++) {
        int idx = base + i;
        if (idx < N_) {
            int rp = exclusive + loc[i];
            rowptr[idx] = rp;
            cursor[idx] = rp;
            dinv[idx] = 1.0f / sqrtf((float)deg[idx] + 1.0f);  // +1 self loop
        }
    }
    if (t == 1023) rowptr[N_] = ssum[1023];
}

// ---------------------------------------------------------------------------
__global__ __launch_bounds__(256) void fill_k(const u32* __restrict__ ei32,
                                              const int* __restrict__ flags,
                                              int* __restrict__ cursor,
                                              int* __restrict__ csr, int E)
{
    int t = blockIdx.x * blockDim.x + threadIdx.x;
    if (t >= E) return;
    int fI = flags[1];
    int s = src_at(ei32, t, E, fI);
    int d = dst_at(ei32, t, E, fI);
    if ((unsigned)d >= (unsigned)N_) return;
    if ((unsigned)s >= (unsigned)N_) s = 0;
    int pos = atomicAdd(&cursor[d], 1);
    if ((unsigned)pos < (unsigned)E) csr[pos] = s;
}

// ---------------------------------------------------------------------------
// GEMM1 v4: H'[b,n,k] = dinv[n] * sum_f x[b,n,f] * W1[f,k], output FP32.
// 4 waves per 64-row tile; wave w owns features [w*128, (w+1)*128) of ALL 64
// rows (lane = row). No LDS staging, no inner barriers: direct global float4
// loads (32 independent per thread, unroll-8 for MLP); W1 index is wave-
// uniform (readfirstlane) -> s_load. One LDS reduction at block end
// (stride-20 words = 80 B, b128-aligned, 2-way-free-ish conflicts, once).
// ---------------------------------------------------------------------------
__global__ __launch_bounds__(256) void gemm1_k(const void* __restrict__ xraw,
                                               const float* __restrict__ w1f,
                                               const float* __restrict__ dinv,
                                               const int* __restrict__ flags,
                                               float* __restrict__ out)
{
    __shared__ float red[3 * 64 * RSTR];   // 15.4 KB
    int t = threadIdx.x;
    int w = __builtin_amdgcn_readfirstlane(t >> 6);   // wave 0..3 (uniform)
    int l = t & 63;                                   // lane = row in tile
    int row = blockIdx.x * RB + l;
    int f0 = w * 128;
    float acc[16];
#pragma unroll
    for (int c = 0; c < 16; c++) acc[c] = 0.0f;

    if (flags[0]) {   // bf16 input: 16 uint4 loads (8 features each)
        const u16* xr = (const u16*)xraw + (size_t)row * F_ + f0;
#pragma unroll 4
        for (int j = 0; j < 16; j++) {
            uint4 pk = *(const uint4*)(xr + j * 8);
            u32 q[4] = {pk.x, pk.y, pk.z, pk.w};
            const float* wr = w1f + (f0 + j * 8) * 16;   // wave-uniform
#pragma unroll
            for (int m = 0; m < 4; m++) {
                float v0 = bf2f((u16)(q[m] & 0xffffu));
                float v1 = bf2f((u16)(q[m] >> 16));
#pragma unroll
                for (int c = 0; c < 16; c++) acc[c] += v0 * wr[2 * m * 16 + c];
#pragma unroll
                for (int c = 0; c < 16; c++) acc[c] += v1 * wr[(2 * m + 1) * 16 + c];
            }
        }
    } else {          // fp32 input: 32 float4 loads (4 features each)
        const float* xr = (const float*)xraw + (size_t)row * F_ + f0;
#pragma unroll 8
        for (int j = 0; j < 32; j++) {
            float4 v = *(const float4*)(xr + j * 4);
            const float* wr = w1f + (f0 + j * 4) * 16;   // wave-uniform
#pragma unroll
            for (int c = 0; c < 16; c++) {
                acc[c] += v.x * wr[c];
                acc[c] += v.y * wr[16 + c];
                acc[c] += v.z * wr[32 + c];
                acc[c] += v.w * wr[48 + c];
            }
        }
    }

    // single cross-wave reduction
    if (w > 0) {
        float* dst = red + ((w - 1) * 64 + l) * RSTR;
#pragma unroll
        for (int c = 0; c < 16; c += 4)
            *(float4*)(dst + c) = make_float4(acc[c], acc[c+1], acc[c+2], acc[c+3]);
    }
    __syncthreads();
    if (w == 0) {
#pragma unroll
        for (int c = 0; c < 16; c++) {
            acc[c] += red[(0 * 64 + l) * RSTR + c]
                    + red[(1 * 64 + l) * RSTR + c]
                    + red[(2 * 64 + l) * RSTR + c];
        }
        float s = dinv[row % N_];
        float* o = out + (size_t)row * 16;
#pragma unroll
        for (int c = 0; c < 16; c += 4)
            *(float4*)(o + c) = make_float4(acc[c]*s, acc[c+1]*s, acc[c+2]*s, acc[c+3]*s);
    }
}

// ---------------------------------------------------------------------------
// Fused agg1 + gemm2 (fp32 H): one WAVE per (b,d); 16 features x 4 edge slots.
//   x1[k] = relu(dinv[d]*(H'[b,d,k] + sum_{s->d} H'[b,s,k]) + b1[k])
//   H2'[b,d,kk] = dinv[d] * sum_k x1[k]*W2[k,kk]
// ---------------------------------------------------------------------------
__global__ __launch_bounds__(256) void agg12_k(const float* __restrict__ h,
                                               const int* __restrict__ rowptr,
                                               const int* __restrict__ csr,
                                               const float* __restrict__ dinv,
                                               const float* __restrict__ b1f,
                                               const float* __restrict__ w2f,
                                               float* __restrict__ out)
{
    int wid = blockIdx.x * 4 + (threadIdx.x >> 6);   // wave id = b*N + d
    int lane = threadIdx.x & 63;
    int k = lane & 15, j = lane >> 4;
    int d = wid % N_;
    int b = wid / N_;
    const float* hb = h + (size_t)b * N_ * 16;
    float acc = (j == 0) ? hb[d * 16 + k] : 0.0f;   // self loop
    int e0 = rowptr[d], e1 = rowptr[d + 1];
    for (int e = e0 + j; e < e1; e += 4) {
        int s = csr[e];
        acc += hb[s * 16 + k];
    }
    acc += __shfl_xor(acc, 16);            // reduce over 4 edge slots
    acc += __shfl_xor(acc, 32);
    float dv = dinv[d];
    float x1 = fmaxf(acc * dv + b1f[k], 0.0f);
    float a2 = 0.0f;
#pragma unroll
    for (int kk = 0; kk < 16; kk++) {
        float xv = __shfl(x1, kk, 16);     // broadcast x1[kk] within 16-group
        a2 += xv * w2f[kk * 16 + k];
    }
    if (lane < 16) out[(size_t)wid * 16 + k] = a2 * dv;
}

// ---------------------------------------------------------------------------
// Fused agg2 + node head + join (fp32 H): one WAVE per (b,d).
//   x2[k] = relu(dinv[d]*(H2'[b,d,k] + sum_s H2'[b,s,k]) + b2[k])
//   nl = sum_k x2[k]*fc_w[k] + fc_b
//   out[b, d*64 + c] = nl + cl[b,c]   (lane c writes, coalesced row)
// ---------------------------------------------------------------------------
__global__ __launch_bounds__(256) void agg2join_k(const float* __restrict__ h,
                                                  const int* __restrict__ rowptr,
                                                  const int* __restrict__ csr,
                                                  const float* __restrict__ dinv,
                                                  const float* __restrict__ b2f,
                                                  const float* __restrict__ fcwf,
                                                  const float* __restrict__ fcbf,
                                                  const float* __restrict__ cl,
                                                  const int* __restrict__ flags,
                                                  void* __restrict__ outraw)
{
    int wid = blockIdx.x * 4 + (threadIdx.x >> 6);   // wave id = b*N + d
    int lane = threadIdx.x & 63;
    int k = lane & 15, j = lane >> 4;
    int d = wid % N_;
    int b = wid / N_;
    const float* hb = h + (size_t)b * N_ * 16;
    float acc = (j == 0) ? hb[d * 16 + k] : 0.0f;
    int e0 = rowptr[d], e1 = rowptr[d + 1];
    for (int e = e0 + j; e < e1; e += 4) {
        int s = csr[e];
        acc += hb[s * 16 + k];
    }
    acc += __shfl_xor(acc, 16);
    acc += __shfl_xor(acc, 32);
    float x2 = fmaxf(acc * dinv[d] + b2f[k], 0.0f);
    float p = x2 * fcwf[k];
    p += __shfl_xor(p, 8, 16);
    p += __shfl_xor(p, 4, 16);
    p += __shfl_xor(p, 2, 16);
    p += __shfl_xor(p, 1, 16);             // all lanes now hold nl
    float nlv = p + fcbf[0];
    float res = nlv + cl[b * C_ + lane];   // lane = column c
    size_t idx = (size_t)wid * C_ + lane;
    if (flags[0]) ((u16*)outraw)[idx] = f2bf(res);
    else          ((float*)outraw)[idx] = res;
}

// ---------------------------------------------------------------------------
extern "C" void kernel_launch(void* const* d_in, const int* in_sizes, int n_in,
                              void* d_out, int out_size, void* d_ws, size_t ws_size,
                              hipStream_t stream)
{
    const void* x    = d_in[0];
    const void* cf   = d_in[1];
    const u32*  ei32 = (const u32*)d_in[2];
    const void* W1   = d_in[3];
    const void* b1   = d_in[4];
    const void* W2   = d_in[5];
    const void* b2   = d_in[6];
    const void* fcw  = d_in[7];
    const void* fcb  = d_in[8];
    const void* cw1  = d_in[9];
    const void* cb1  = d_in[10];
    const void* cw2  = d_in[11];
    const void* cb2  = d_in[12];

    const int E = in_sizes[2] / 2;

    char* base = (char*)d_ws;
    size_t off = 0;
    auto alloc = [&](size_t bytes) -> void* {
        void* p = base + off;
        off = (off + bytes + 255) & ~(size_t)255;
        return p;
    };
    int*   flags  = (int*)alloc(2 * 4);
    float* w1f  = (float*)alloc(8192 * 4);
    float* w2f  = (float*)alloc(256 * 4);
    float* fcwf = (float*)alloc(16 * 4);
    float* cw1f = (float*)alloc(2048 * 4);
    float* cw2f = (float*)alloc(16 * 4);
    float* b1f  = (float*)alloc(16 * 4);
    float* b2f  = (float*)alloc(16 * 4);
    float* fcbf = (float*)alloc(4);
    float* cb1f = (float*)alloc(16 * 4);
    float* cb2f = (float*)alloc(4);
    int*   deg    = (int*)alloc((size_t)N_ * 4);
    int*   rowptr = (int*)alloc((size_t)(N_ + 1) * 4);
    int*   cursor = (int*)alloc((size_t)N_ * 4);
    float* dinv   = (float*)alloc((size_t)N_ * 4);
    int*   csr    = (int*)alloc((size_t)E * 4);
    float* bufA = (float*)alloc((size_t)NT * 16 * 4);   // H'  (fp32)
    float* bufB = (float*)alloc((size_t)NT * 16 * 4);   // H2' (fp32)
    float* cl   = (float*)alloc((size_t)B_ * C_ * 4);

    const int colB0 = (E + 255) / 256;   // deg blocks; col blocks appended

    setup_k<<<1, 256, 0, stream>>>(
        (const u32*)x, ei32, W1, W2, fcw, cw1, cw2, b1, b2, fcb, cb1, cb2,
        flags, deg,
        w1f, w2f, fcwf, cw1f, cw2f, b1f, b2f, fcbf, cb1f, cb2f);
    degcol_k<<<colB0 + (B_ * C_ + 255) / 256, 256, 0, stream>>>(
        ei32, flags, deg, E, colB0, cf, cw1f, cb1f, cw2f, cb2f, cl);
    scan_k<<<1, 1024, 0, stream>>>(deg, rowptr, cursor, dinv);
    fill_k<<<(E + 255) / 256, 256, 0, stream>>>(ei32, flags, cursor, csr, E);

    gemm1_k<<<NT / RB, 256, 0, stream>>>(x, w1f, dinv, flags, bufA);
    agg12_k<<<NT / 4, 256, 0, stream>>>(bufA, rowptr, csr, dinv, b1f, w2f, bufB);
    agg2join_k<<<NT / 4, 256, 0, stream>>>(bufB, rowptr, csr, dinv, b2f, fcwf, fcbf, cl, flags, d_out);
}